// Round 4
// baseline (363.108 us; speedup 1.0000x reference)
//
#include <hip/hip_runtime.h>
#include <math.h>

// Attention pooling: context[b,d] = sum_t softmax_t( V . tanh(full[b,t,:]@W1 + last[b,:]@W2 + b1+b2) ) * full[b,t,d]
// B=32 T=2048 D=512 U=512, fp32 in/out. bV softmax-invariant -> dropped; b1+b2 folded into h2.
// R11: TWO independent barrier domains per CU (m114/m132: co-resident blocks, not intra-block
//   pipelining, is what hides the barrier drain; R8-R10 all had 1 block/CU = fully exposed drains).
//   Block shrunk to 8 waves / M=64 (wave tile 64x64, acc[4][4]=64 AGPR, combined ~128 regs ->
//   16 waves/CU allowed). LDS diet to 71.7 KB: A single-buffered bf16 4 KB (write sits between
//   the two per-step barriers), B dbuf 64 KB, epilogue scratch ALIASED into blds (dead after
//   K-loop). -> 2 blocks/CU by both LDS and regs. Block does its 128-row tile as two sequential
//   64-row halves + in-block flash merge, so grid/ws/combine unchanged.
// ws (floats): h2 [B*U] @0, m_arr [512] @16384, l_arr [512] @16896, ctx [B*16*D] @17408,
//              W1T [U*D] bf16 @ float-offset 279552. Total ~1.64 MB.

#define BB 32
#define TT 2048
#define DD 512
#define UU 512
#define BKK 32
#define KSTEPS 16

typedef short bf16x8 __attribute__((ext_vector_type(8)));
typedef short s16x4  __attribute__((ext_vector_type(4)));
typedef float f32x4  __attribute__((ext_vector_type(4)));

static __device__ __forceinline__ short f2bf(float f) {
    unsigned x = __float_as_uint(f);
    return (short)((x + 0x7fffu + ((x >> 16) & 1u)) >> 16);   // RNE
}

static __device__ __forceinline__ float fast_tanh(float x) {
    float e = __expf(2.f * x);
    return 1.f - 2.f * __builtin_amdgcn_rcpf(e + 1.f);
}

// ---------------- prep ----------------
// blocks [0,256): W1T[u][d] = bf16(W1[d][u]) tile-transposed
// blocks [256,384): h2 slice — block owns (b, 128-u-slice); threads d-split x2 + LDS combine
__global__ __launch_bounds__(256) void prep_kernel(const float* __restrict__ W1,
                                                   short* __restrict__ W1T,
                                                   const float* __restrict__ last,
                                                   const float* __restrict__ W2,
                                                   const float* __restrict__ b1,
                                                   const float* __restrict__ b2,
                                                   float* __restrict__ h2) {
    __shared__ float tile[32][33];
    __shared__ float ls[DD];
    __shared__ float part[256];
    const int bid = blockIdx.x;
    const int tid = threadIdx.x;
    if (bid < 256) {
        const int tr = (bid >> 4) << 5;   // d-block origin
        const int tc = (bid & 15) << 5;   // u-block origin
#pragma unroll
        for (int p = 0; p < 4; ++p) {
            const int r = p * 8 + (tid >> 5), c = tid & 31;
            tile[r][c] = W1[(size_t)(tr + r) * UU + tc + c];
        }
        __syncthreads();
#pragma unroll
        for (int p = 0; p < 4; ++p) {
            const int r = p * 8 + (tid >> 5), c = tid & 31;    // r=u-local, c=d-local
            W1T[(size_t)(tc + r) * DD + tr + c] = f2bf(tile[c][r]);
        }
    } else {
        const int b2i = bid - 256;
        const int b  = b2i >> 2;
        const int u0 = (b2i & 3) << 7;
        for (int i = tid; i < DD; i += 256) ls[i] = last[b * DD + i];
        __syncthreads();
        const int uu = tid & 127;
        const int dh = tid >> 7;
        float acc = 0.f;
#pragma unroll 8
        for (int d = dh * 256; d < dh * 256 + 256; ++d)
            acc += ls[d] * W2[d * UU + u0 + uu];
        part[tid] = acc;
        __syncthreads();
        if (tid < 128) {
            const int u = u0 + tid;
            h2[b * UU + u] = part[tid] + part[tid + 128] + b1[u] + b2[u];
        }
    }
}

// ---------------- score + partial context (flash-style, 2 halves/block) ----------------
// 512 blocks: b = bid>>4, tile = bid&15. 512 threads = 8 waves, each wave an n-slice of 64 u;
// wave tile 64(M) x 64(N), acc[4][4]. Per half (64 t-rows): K-loop BK=32, 16 steps:
//   P1 ds_read af[4](A bf16, single buf) + bfr[4](B dbuf)  -> lgkm(0)+schedbar+s_barrier
//   P3 vmcnt(4) [A(ko+1) reg landed] -> ds_write A(ko+1) into a16
//   P4 global_load f32x4 A(ko+2) (1/thread)
//   P5 global_load_lds B(ko+2) -> blds[cur] (4/thread)
//   P6 16 MFMA
//   P7 vmcnt(5) [B(ko+1) landed] + lgkm(0) + s_barrier     (tail: ko==14 -> vmcnt(0))
// Then per half: tanh+V scores -> wave0 softmax (m_h, l_h, esc) -> partial ctx from L2-hot rows.
// Half 0 parks ctx in LDS; half 1 flash-merges and writes ctx[bid]/m_arr/l_arr.
// LDS 71.7 KB: a16 4K | blds 64K (epilogue scratch aliased inside) | ctxH 2K | mlh 16B.
__global__ __launch_bounds__(512, 4) void score_kernel(const float* __restrict__ full,
                                                       const short* __restrict__ W1T,
                                                       const float* __restrict__ h2,
                                                       const float* __restrict__ V,
                                                       float* __restrict__ ctx,
                                                       float* __restrict__ m_arr,
                                                       float* __restrict__ l_arr) {
    __shared__ __align__(16) char smem[71712];
    short* a16  = (short*)smem;                              // [64*32] bf16 A, single buffer
    short* blds = (short*)(smem + 4096);                     // [2][512*32] bf16 B
    float* ctxH = (float*)(smem + 4096 + 65536);             // [512] half-0 partial context
    float* mlh  = (float*)(smem + 4096 + 65536 + 2048);      // [4]: m0,l0,m1,l1
    // epilogue scratch aliased into the blds region (dead after K-loop final barrier):
    float (*red64)[64]    = (float(*)[64])(smem + 4096);                 // 2048 B
    float* esc            = (float*)(smem + 4096 + 2048);                // 256 B
    float (*red4)[128][4] = (float(*)[128][4])(smem + 4096 + 2304);      // 8192 B

    const int bid  = blockIdx.x;
    const int b    = bid >> 4;
    const int t0   = (bid & 15) << 7;
    const int tid  = threadIdx.x;
    const int w    = tid >> 6;          // 0..7 = n-slice
    const int lane = tid & 63;
    const int quad = lane >> 4;
    const int col  = lane & 15;

    // A reg-staging mapping: thread -> (row sr 0..63, 4-float group se 0..7)
    const int sr = tid >> 3;
    const int se = tid & 7;
    // swizzled LDS write offset (shorts): chunk = se>>1 -> chunk^(sr&3); half-chunk = se&1
    const int awOff = sr * 32 + ((((se >> 1) ^ (sr & 3)) << 3) + ((se & 1) << 2));

    // B DMA: 2048 bf16x8 chunks/buffer, 4 issues/thread
#define STAGE_B(bufidx, koidx) do {                                                   \
        _Pragma("unroll")                                                             \
        for (int i = 0; i < 4; ++i) {                                                 \
            const int sb = w * 256 + i * 64;                                          \
            const int s  = sb + lane;                                                 \
            const int u  = s >> 2;                                                    \
            const int kc = (s & 3) ^ ((u >> 1) & 3);                                  \
            const short* g = &W1T[(size_t)u * DD + (koidx) * BKK + kc * 8];           \
            __builtin_amdgcn_global_load_lds(                                         \
                (const __attribute__((address_space(1))) void*)g,                     \
                (__attribute__((address_space(3))) void*)&blds[(bufidx) * 16384 + sb * 8], 16, 0, 0); \
        }                                                                             \
    } while (0)

#define CVT_WRITE(ar) do {                                                            \
        s16x4 q_ = (s16x4){f2bf((ar).x), f2bf((ar).y), f2bf((ar).z), f2bf((ar).w)};   \
        *(s16x4*)&a16[awOff] = q_;                                                    \
    } while (0)

    for (int h = 0; h < 2; ++h) {
        const size_t rowbase = (size_t)(b * TT + t0 + h * 64) * DD;
        const float* aSrc = &full[rowbase + (size_t)sr * DD + se * 4];

        f32x4 acc[4][4];
#pragma unroll
        for (int i = 0; i < 4; ++i)
#pragma unroll
            for (int j = 0; j < 4; ++j) acc[i][j] = (f32x4){0.f, 0.f, 0.f, 0.f};

        // ---- prologue: A(0),A(1) reg loads; B(0),B(1) DMA; write A(0); wait B(0) ----
        f32x4 aregA = *(const f32x4*)(aSrc + 0 * BKK);
        f32x4 aregB = *(const f32x4*)(aSrc + 1 * BKK);
        __builtin_amdgcn_sched_barrier(0);               // pin issue order: A regs before B DMA
        STAGE_B(0, 0);
        STAGE_B(1, 1);
        __builtin_amdgcn_sched_barrier(0);
        asm volatile("s_waitcnt vmcnt(9)" ::: "memory"); // A(0) landed (oldest of 10)
        CVT_WRITE(aregA);
        asm volatile("s_waitcnt vmcnt(4)" ::: "memory"); // A(1)+B(0) landed (B(1) flying)
        asm volatile("s_waitcnt lgkmcnt(0)" ::: "memory");
        __builtin_amdgcn_s_barrier();

        for (int ko = 0; ko < KSTEPS; ++ko) {
            const int cur = ko & 1;
            // ---- P1: ds_read fragments ----
            bf16x8 af[4], bfr[4];
#pragma unroll
            for (int mt = 0; mt < 4; ++mt) {
                const int r = mt * 16 + col;
                af[mt] = *(const bf16x8*)&a16[r * 32 + ((quad ^ (r & 3)) << 3)];
            }
#pragma unroll
            for (int nt = 0; nt < 4; ++nt) {
                const int u = w * 64 + nt * 16 + col;
                bfr[nt] = *(const bf16x8*)&blds[cur * 16384 + (u * 4 + (quad ^ ((u >> 1) & 3))) * 8];
            }
            asm volatile("s_waitcnt lgkmcnt(0)" ::: "memory");
            __builtin_amdgcn_sched_barrier(0);           // rule 18
            __builtin_amdgcn_s_barrier();                // all waves done reading a16 + blds[cur]

            // ---- P3: write A(ko+1) into a16 (between the two barriers -> single buffer ok) ----
            if (ko + 1 < KSTEPS) {
                asm volatile("s_waitcnt vmcnt(4)" ::: "memory");  // A(ko+1) reg landed
                if (ko & 1) CVT_WRITE(aregA);
                else        CVT_WRITE(aregB);
            }
            // ---- P4: issue A(ko+2) into the freed reg ----
            if (ko + 2 < KSTEPS) {
                if (ko & 1) aregB = *(const f32x4*)(aSrc + (ko + 2) * BKK);
                else        aregA = *(const f32x4*)(aSrc + (ko + 2) * BKK);
            }
            // ---- P5: issue B(ko+2) DMA into blds[cur] ----
            if (ko + 2 < KSTEPS) STAGE_B(cur, ko + 2);

            // ---- P6: MFMA ----
#pragma unroll
            for (int nt = 0; nt < 4; ++nt)
#pragma unroll
                for (int mt = 0; mt < 4; ++mt)
                    acc[mt][nt] = __builtin_amdgcn_mfma_f32_16x16x32_bf16(af[mt], bfr[nt], acc[mt][nt], 0, 0, 0);

            // ---- P7: counted wait for B(ko+1); drain my ds_write; barrier ----
            if (ko < KSTEPS - 2) {
                asm volatile("s_waitcnt vmcnt(5)" ::: "memory");
            } else if (ko == KSTEPS - 2) {
                asm volatile("s_waitcnt vmcnt(0)" ::: "memory");
            }
            if (ko < KSTEPS - 1) {
                asm volatile("s_waitcnt lgkmcnt(0)" ::: "memory");
                __builtin_amdgcn_s_barrier();
            }
        }

        // ---- raw scores: tanh + V-dot over this wave's 64 u, all 64 rows ----
        float srow[16];
#pragma unroll
        for (int i = 0; i < 16; ++i) srow[i] = 0.f;
#pragma unroll
        for (int nt = 0; nt < 4; ++nt) {
            const int u = w * 64 + nt * 16 + col;
            const float hv = h2[b * UU + u];
            const float vv = V[u];
#pragma unroll
            for (int mt = 0; mt < 4; ++mt)
#pragma unroll
                for (int r = 0; r < 4; ++r)
                    srow[mt * 4 + r] += fast_tanh(acc[mt][nt][r] + hv) * vv;
        }
#pragma unroll
        for (int off = 1; off < 16; off <<= 1) {
#pragma unroll
            for (int i = 0; i < 16; ++i) srow[i] += __shfl_xor(srow[i], off, 64);
        }
        __syncthreads();      // K-loop fully done block-wide -> safe to reuse blds as scratch
        if (col == 0) {
#pragma unroll
            for (int mt = 0; mt < 4; ++mt)
#pragma unroll
                for (int r = 0; r < 4; ++r)
                    red64[w][mt * 16 + quad * 4 + r] = srow[mt * 4 + r];
        }
        __syncthreads();

        // ---- softmax stats for this half: wave 0 handles all 64 rows ----
        if (tid < 64) {
            float sv = 0.f;
#pragma unroll
            for (int j = 0; j < 8; ++j) sv += red64[j][lane];
            float mv = sv;
#pragma unroll
            for (int off = 1; off < 64; off <<= 1) mv = fmaxf(mv, __shfl_xor(mv, off, 64));
            float e = __expf(sv - mv);
            esc[lane] = e;
            float l = e;
#pragma unroll
            for (int off = 1; off < 64; off <<= 1) l += __shfl_xor(l, off, 64);
            if (lane == 0) { mlh[h * 2] = mv; mlh[h * 2 + 1] = l; }
        }
        __syncthreads();

        // ---- partial context from the (L2-hot) half-tile: ctx[d] = sum_t esc[t]*full[t,d] ----
        const int c  = tid & 127;             // float4 column, d = c*4
        const int tp = tid >> 7;              // t residue mod 4
        float ax = 0.f, ay = 0.f, az = 0.f, aw = 0.f;
#pragma unroll 4
        for (int i = 0; i < 16; ++i) {
            const int t = i * 4 + tp;
            const float4 v = *(const float4*)&full[rowbase + (size_t)t * DD + c * 4];
            const float e = esc[t];
            ax += e * v.x; ay += e * v.y; az += e * v.z; aw += e * v.w;
        }
        *(float4*)&red4[tp][c][0] = make_float4(ax, ay, az, aw);
        __syncthreads();
        if (tp == 0) {
            const float4 p0 = *(const float4*)&red4[0][c][0];
            const float4 p1 = *(const float4*)&red4[1][c][0];
            const float4 p2 = *(const float4*)&red4[2][c][0];
            const float4 p3 = *(const float4*)&red4[3][c][0];
            float4 s = make_float4(p0.x + p1.x + p2.x + p3.x,
                                   p0.y + p1.y + p2.y + p3.y,
                                   p0.z + p1.z + p2.z + p3.z,
                                   p0.w + p1.w + p2.w + p3.w);
            if (h == 0) {
                *(float4*)&ctxH[c * 4] = s;
            } else {
                const float m0 = mlh[0], l0 = mlh[1], m1 = mlh[2], l1 = mlh[3];
                const float M  = fmaxf(m0, m1);
                const float w0 = __expf(m0 - M), w1 = __expf(m1 - M);
                const float4 p = *(const float4*)&ctxH[c * 4];
                float4 o = make_float4(w0 * p.x + w1 * s.x, w0 * p.y + w1 * s.y,
                                       w0 * p.z + w1 * s.z, w0 * p.w + w1 * s.w);
                *(float4*)&ctx[(size_t)bid * DD + c * 4] = o;
                if (tid == 0) { m_arr[bid] = M; l_arr[bid] = w0 * l0 + w1 * l1; }
            }
        }
        __syncthreads();      // protect ctxH/red4/esc before next half's staging overwrites
    }
#undef STAGE_B
#undef CVT_WRITE
}

// ---------------- combine: out[b,d] = sum_i w_i*ctx[b,i,d] / sum_i w_i*l_i, w_i = e^{m_i - M} ----------------
__global__ __launch_bounds__(256) void combine_kernel(const float* __restrict__ ctx,
                                                      const float* __restrict__ m_arr,
                                                      const float* __restrict__ l_arr,
                                                      float* __restrict__ out) {
    const int b = blockIdx.x;
    const int tid = threadIdx.x;
    __shared__ float wgt[16];
    __shared__ float linv;
    if (tid == 0) {
        float M = -1e30f;
#pragma unroll
        for (int i = 0; i < 16; ++i) M = fmaxf(M, m_arr[b * 16 + i]);
        float l = 0.f;
#pragma unroll
        for (int i = 0; i < 16; ++i) {
            wgt[i] = __expf(m_arr[b * 16 + i] - M);
            l += wgt[i] * l_arr[b * 16 + i];
        }
        linv = 1.f / l;
    }
    __syncthreads();
    float s0 = 0.f, s1 = 0.f;
#pragma unroll
    for (int i = 0; i < 16; ++i) {
        const float wi = wgt[i];
        const float* cp = &ctx[(size_t)(b * 16 + i) * DD + tid * 2];
        s0 += wi * cp[0];
        s1 += wi * cp[1];
    }
    out[b * DD + tid * 2]     = s0 * linv;
    out[b * DD + tid * 2 + 1] = s1 * linv;
}

extern "C" void kernel_launch(void* const* d_in, const int* in_sizes, int n_in,
                              void* d_out, int out_size, void* d_ws, size_t ws_size,
                              hipStream_t stream) {
    const float* full = (const float*)d_in[0];
    const float* last = (const float*)d_in[1];
    const float* W1   = (const float*)d_in[2];
    const float* b1   = (const float*)d_in[3];
    const float* W2   = (const float*)d_in[4];
    const float* b2   = (const float*)d_in[5];
    const float* V    = (const float*)d_in[6];
    // d_in[7] = bV: softmax-invariant, unused.

    float* out   = (float*)d_out;
    float* h2    = (float*)d_ws;                    // 16384 floats
    float* m_arr = h2 + (size_t)BB * UU;            // 512
    float* l_arr = m_arr + 512;                     // 512
    float* ctx   = l_arr + 512;                     // 32*16*512 = 262144
    short* W1T   = (short*)(ctx + (size_t)BB * 16 * DD);  // U*D bf16

    prep_kernel<<<384, 256, 0, stream>>>(W1, W1T, last, W2, b1, b2, h2);
    score_kernel<<<BB * 16, 512, 0, stream>>>(full, W1T, h2, V, ctx, m_arr, l_arr);
    combine_kernel<<<BB, 256, 0, stream>>>(ctx, m_arr, l_arr, out);
}

// Round 5
// 282.654 us; speedup vs baseline: 1.2846x; 1.2846x over previous
//
#include <hip/hip_runtime.h>
#include <math.h>

// Attention pooling: context[b,d] = sum_t softmax_t( V . tanh(full[b,t,:]@W1 + last[b,:]@W2 + b1+b2) ) * full[b,t,d]
// B=32 T=2048 D=512 U=512, fp32 in/out. bV softmax-invariant -> dropped; b1+b2 folded into h2.
// R12: R11's occupancy structure (2 blocks/CU proven to stream 2.46 TB/s) WITHOUT the h-loop that
//   caused its ~180 MB symmetric spill round-trip (FETCH+WRITE both +180 MB = scratch signature).
//   Grid 1024 blocks, each owns ONE 64-row tile; body = R11's inner half exactly (register profile
//   of clean R10). LDS 68 KB: A single-buf bf16 4 KB + B dbuf 64 KB, epilogue scratch aliased into
//   blds (dead after K-loop's last in-loop barrier). ctx partials [1024][512]; combine merges 32.
// ws (floats): h2 [16384] @0, m_arr [1024] @16384, l_arr [1024] @17408, ctx [1024*512] @18432,
//              W1T [U*D bf16] @ float-offset 542720. Total ~2.57 MB.

#define BB 32
#define TT 2048
#define DD 512
#define UU 512
#define BKK 32
#define KSTEPS 16

typedef short bf16x8 __attribute__((ext_vector_type(8)));
typedef short s16x4  __attribute__((ext_vector_type(4)));
typedef float f32x4  __attribute__((ext_vector_type(4)));

static __device__ __forceinline__ short f2bf(float f) {
    unsigned x = __float_as_uint(f);
    return (short)((x + 0x7fffu + ((x >> 16) & 1u)) >> 16);   // RNE
}

static __device__ __forceinline__ float fast_tanh(float x) {
    float e = __expf(2.f * x);
    return 1.f - 2.f * __builtin_amdgcn_rcpf(e + 1.f);
}

// ---------------- prep ----------------
// blocks [0,256): W1T[u][d] = bf16(W1[d][u]) tile-transposed
// blocks [256,384): h2 slice — block owns (b, 128-u-slice); threads d-split x2 + LDS combine
__global__ __launch_bounds__(256) void prep_kernel(const float* __restrict__ W1,
                                                   short* __restrict__ W1T,
                                                   const float* __restrict__ last,
                                                   const float* __restrict__ W2,
                                                   const float* __restrict__ b1,
                                                   const float* __restrict__ b2,
                                                   float* __restrict__ h2) {
    __shared__ float tile[32][33];
    __shared__ float ls[DD];
    __shared__ float part[256];
    const int bid = blockIdx.x;
    const int tid = threadIdx.x;
    if (bid < 256) {
        const int tr = (bid >> 4) << 5;   // d-block origin
        const int tc = (bid & 15) << 5;   // u-block origin
#pragma unroll
        for (int p = 0; p < 4; ++p) {
            const int r = p * 8 + (tid >> 5), c = tid & 31;
            tile[r][c] = W1[(size_t)(tr + r) * UU + tc + c];
        }
        __syncthreads();
#pragma unroll
        for (int p = 0; p < 4; ++p) {
            const int r = p * 8 + (tid >> 5), c = tid & 31;    // r=u-local, c=d-local
            W1T[(size_t)(tc + r) * DD + tr + c] = f2bf(tile[c][r]);
        }
    } else {
        const int b2i = bid - 256;
        const int b  = b2i >> 2;
        const int u0 = (b2i & 3) << 7;
        for (int i = tid; i < DD; i += 256) ls[i] = last[b * DD + i];
        __syncthreads();
        const int uu = tid & 127;
        const int dh = tid >> 7;
        float acc = 0.f;
#pragma unroll 8
        for (int d = dh * 256; d < dh * 256 + 256; ++d)
            acc += ls[d] * W2[d * UU + u0 + uu];
        part[tid] = acc;
        __syncthreads();
        if (tid < 128) {
            const int u = u0 + tid;
            h2[b * UU + u] = part[tid] + part[tid + 128] + b1[u] + b2[u];
        }
    }
}

// ---------------- score + partial context (flash-style, one 64-row tile per block) ----------------
// 1024 blocks: b = bid>>5, t0 = (bid&31)*64. 512 threads = 8 waves, each wave one 64-u n-slice;
// wave tile 64(M) x 64(N), acc[4][4]. K-loop BK=32, 16 steps:
//   P1 ds_read af[4](A bf16, single buf) + bfr[4](B dbuf)  -> lgkm(0)+schedbar+s_barrier
//   P3 vmcnt(4) [A(ko+1) reg landed] -> ds_write A(ko+1) into a16
//   P4 global_load f32x4 A(ko+2) (1/thread)
//   P5 global_load_lds B(ko+2) -> blds[cur] (4/thread)
//   P6 16 MFMA
//   P7 vmcnt(5) [B(ko+1) landed] + lgkm(0) + s_barrier     (tail: ko==14 -> vmcnt(0))
// Epilogue: tanh+V scores -> wave0 softmax (m,l,esc) -> partial ctx from the L2-hot 64 rows.
// LDS 68 KB: a16 4K | blds 64K (red64/esc/red4 aliased inside, dead after K-loop).
__global__ __launch_bounds__(512, 4) void score_kernel(const float* __restrict__ full,
                                                       const short* __restrict__ W1T,
                                                       const float* __restrict__ h2,
                                                       const float* __restrict__ V,
                                                       float* __restrict__ ctx,
                                                       float* __restrict__ m_arr,
                                                       float* __restrict__ l_arr) {
    __shared__ __align__(16) char smem[69632];
    short* a16  = (short*)smem;                              // [64*32] bf16 A, single buffer
    short* blds = (short*)(smem + 4096);                     // [2][512*32] bf16 B
    // epilogue scratch aliased into the blds region (dead after K-loop final in-loop barrier):
    float (*red64)[64]    = (float(*)[64])(smem + 4096);             // 2048 B
    float* esc            = (float*)(smem + 4096 + 2048);            // 256 B
    float (*red4)[128][4] = (float(*)[128][4])(smem + 4096 + 2304);  // 8192 B (16B-aligned: 6400%16==0)

    const int bid  = blockIdx.x;
    const int b    = bid >> 5;
    const int t0   = (bid & 31) << 6;
    const int tid  = threadIdx.x;
    const int w    = tid >> 6;          // 0..7 = n-slice
    const int lane = tid & 63;
    const int quad = lane >> 4;
    const int col  = lane & 15;

    const size_t rowbase = (size_t)(b * TT + t0) * DD;

    // A reg-staging mapping: thread -> (row sr 0..63, 4-float group se 0..7)
    const int sr = tid >> 3;
    const int se = tid & 7;
    const float* aSrc = &full[rowbase + (size_t)sr * DD + se * 4];
    // swizzled LDS write offset (shorts): chunk = se>>1 -> chunk^(sr&3); half-chunk = se&1
    const int awOff = sr * 32 + ((((se >> 1) ^ (sr & 3)) << 3) + ((se & 1) << 2));

    f32x4 acc[4][4];
#pragma unroll
    for (int i = 0; i < 4; ++i)
#pragma unroll
        for (int j = 0; j < 4; ++j) acc[i][j] = (f32x4){0.f, 0.f, 0.f, 0.f};

    // B DMA: 2048 bf16x8 chunks/buffer, 4 issues/thread
#define STAGE_B(bufidx, koidx) do {                                                   \
        _Pragma("unroll")                                                             \
        for (int i = 0; i < 4; ++i) {                                                 \
            const int sb = w * 256 + i * 64;                                          \
            const int s  = sb + lane;                                                 \
            const int u  = s >> 2;                                                    \
            const int kc = (s & 3) ^ ((u >> 1) & 3);                                  \
            const short* g = &W1T[(size_t)u * DD + (koidx) * BKK + kc * 8];           \
            __builtin_amdgcn_global_load_lds(                                         \
                (const __attribute__((address_space(1))) void*)g,                     \
                (__attribute__((address_space(3))) void*)&blds[(bufidx) * 16384 + sb * 8], 16, 0, 0); \
        }                                                                             \
    } while (0)

#define CVT_WRITE(ar) do {                                                            \
        s16x4 q_ = (s16x4){f2bf((ar).x), f2bf((ar).y), f2bf((ar).z), f2bf((ar).w)};   \
        *(s16x4*)&a16[awOff] = q_;                                                    \
    } while (0)

    // ---- prologue: A(0),A(1) reg loads; B(0),B(1) DMA; write A(0); wait B(0) ----
    f32x4 aregA = *(const f32x4*)(aSrc + 0 * BKK);
    f32x4 aregB = *(const f32x4*)(aSrc + 1 * BKK);
    __builtin_amdgcn_sched_barrier(0);               // pin issue order: A regs before B DMA
    STAGE_B(0, 0);
    STAGE_B(1, 1);
    __builtin_amdgcn_sched_barrier(0);
    asm volatile("s_waitcnt vmcnt(9)" ::: "memory"); // A(0) landed (oldest of 10)
    CVT_WRITE(aregA);
    asm volatile("s_waitcnt vmcnt(4)" ::: "memory"); // A(1)+B(0) landed (B(1) flying)
    asm volatile("s_waitcnt lgkmcnt(0)" ::: "memory");
    __builtin_amdgcn_s_barrier();

    for (int ko = 0; ko < KSTEPS; ++ko) {
        const int cur = ko & 1;
        // ---- P1: ds_read fragments ----
        bf16x8 af[4], bfr[4];
#pragma unroll
        for (int mt = 0; mt < 4; ++mt) {
            const int r = mt * 16 + col;
            af[mt] = *(const bf16x8*)&a16[r * 32 + ((quad ^ (r & 3)) << 3)];
        }
#pragma unroll
        for (int nt = 0; nt < 4; ++nt) {
            const int u = w * 64 + nt * 16 + col;
            bfr[nt] = *(const bf16x8*)&blds[cur * 16384 + (u * 4 + (quad ^ ((u >> 1) & 3))) * 8];
        }
        asm volatile("s_waitcnt lgkmcnt(0)" ::: "memory");
        __builtin_amdgcn_sched_barrier(0);           // rule 18
        __builtin_amdgcn_s_barrier();                // all waves done reading a16 + blds[cur]

        // ---- P3: write A(ko+1) into a16 (between the two barriers -> single buffer ok) ----
        if (ko + 1 < KSTEPS) {
            asm volatile("s_waitcnt vmcnt(4)" ::: "memory");  // A(ko+1) reg landed
            if (ko & 1) CVT_WRITE(aregA);
            else        CVT_WRITE(aregB);
        }
        // ---- P4: issue A(ko+2) into the freed reg ----
        if (ko + 2 < KSTEPS) {
            if (ko & 1) aregB = *(const f32x4*)(aSrc + (ko + 2) * BKK);
            else        aregA = *(const f32x4*)(aSrc + (ko + 2) * BKK);
        }
        // ---- P5: issue B(ko+2) DMA into blds[cur] ----
        if (ko + 2 < KSTEPS) STAGE_B(cur, ko + 2);

        // ---- P6: MFMA ----
#pragma unroll
        for (int nt = 0; nt < 4; ++nt)
#pragma unroll
            for (int mt = 0; mt < 4; ++mt)
                acc[mt][nt] = __builtin_amdgcn_mfma_f32_16x16x32_bf16(af[mt], bfr[nt], acc[mt][nt], 0, 0, 0);

        // ---- P7: counted wait for B(ko+1); drain my ds_write; barrier ----
        if (ko < KSTEPS - 2) {
            asm volatile("s_waitcnt vmcnt(5)" ::: "memory");
        } else if (ko == KSTEPS - 2) {
            asm volatile("s_waitcnt vmcnt(0)" ::: "memory");
        }
        if (ko < KSTEPS - 1) {
            asm volatile("s_waitcnt lgkmcnt(0)" ::: "memory");
            __builtin_amdgcn_s_barrier();
        }
    }
#undef STAGE_B
#undef CVT_WRITE

    // ---- raw scores: tanh + V-dot over this wave's 64 u, all 64 rows ----
    float srow[16];
#pragma unroll
    for (int i = 0; i < 16; ++i) srow[i] = 0.f;
#pragma unroll
    for (int nt = 0; nt < 4; ++nt) {
        const int u = w * 64 + nt * 16 + col;
        const float hv = h2[b * UU + u];
        const float vv = V[u];
#pragma unroll
        for (int mt = 0; mt < 4; ++mt)
#pragma unroll
            for (int r = 0; r < 4; ++r)
                srow[mt * 4 + r] += fast_tanh(acc[mt][nt][r] + hv) * vv;
    }
#pragma unroll
    for (int off = 1; off < 16; off <<= 1) {
#pragma unroll
        for (int i = 0; i < 16; ++i) srow[i] += __shfl_xor(srow[i], off, 64);
    }
    // K-loop reads all completed before the last in-loop s_barrier -> blds reusable as scratch.
    if (col == 0) {
#pragma unroll
        for (int mt = 0; mt < 4; ++mt)
#pragma unroll
            for (int r = 0; r < 4; ++r)
                red64[w][mt * 16 + quad * 4 + r] = srow[mt * 4 + r];
    }
    __syncthreads();

    // ---- softmax stats: wave 0 handles all 64 rows ----
    if (tid < 64) {
        float sv = 0.f;
#pragma unroll
        for (int j = 0; j < 8; ++j) sv += red64[j][lane];
        float mv = sv;
#pragma unroll
        for (int off = 1; off < 64; off <<= 1) mv = fmaxf(mv, __shfl_xor(mv, off, 64));
        float e = __expf(sv - mv);
        esc[lane] = e;
        float l = e;
#pragma unroll
        for (int off = 1; off < 64; off <<= 1) l += __shfl_xor(l, off, 64);
        if (lane == 0) { m_arr[bid] = mv; l_arr[bid] = l; }
    }
    __syncthreads();

    // ---- partial context from the (L2-hot) tile: ctx[d] = sum_t esc[t] * full[t,d] ----
    const int c  = tid & 127;             // float4 column, d = c*4
    const int tp = tid >> 7;              // t residue mod 4
    float ax = 0.f, ay = 0.f, az = 0.f, aw = 0.f;
#pragma unroll 4
    for (int i = 0; i < 16; ++i) {
        const int t = i * 4 + tp;
        const float4 v = *(const float4*)&full[rowbase + (size_t)t * DD + c * 4];
        const float e = esc[t];
        ax += e * v.x; ay += e * v.y; az += e * v.z; aw += e * v.w;
    }
    *(float4*)&red4[tp][c][0] = make_float4(ax, ay, az, aw);
    __syncthreads();
    if (tp == 0) {
        const float4 p0 = *(const float4*)&red4[0][c][0];
        const float4 p1 = *(const float4*)&red4[1][c][0];
        const float4 p2 = *(const float4*)&red4[2][c][0];
        const float4 p3 = *(const float4*)&red4[3][c][0];
        float4 s = make_float4(p0.x + p1.x + p2.x + p3.x,
                               p0.y + p1.y + p2.y + p3.y,
                               p0.z + p1.z + p2.z + p3.z,
                               p0.w + p1.w + p2.w + p3.w);
        *(float4*)&ctx[(size_t)bid * DD + c * 4] = s;
    }
}

// ---------------- combine: out[b,d] = sum_i w_i*ctx[b,i,d] / sum_i w_i*l_i, w_i = e^{m_i - M} ----------------
__global__ __launch_bounds__(256) void combine_kernel(const float* __restrict__ ctx,
                                                      const float* __restrict__ m_arr,
                                                      const float* __restrict__ l_arr,
                                                      float* __restrict__ out) {
    const int b = blockIdx.x;
    const int tid = threadIdx.x;
    __shared__ float wgt[32];
    __shared__ float linv;
    if (tid == 0) {
        float M = -1e30f;
#pragma unroll
        for (int i = 0; i < 32; ++i) M = fmaxf(M, m_arr[b * 32 + i]);
        float l = 0.f;
#pragma unroll
        for (int i = 0; i < 32; ++i) {
            wgt[i] = __expf(m_arr[b * 32 + i] - M);
            l += wgt[i] * l_arr[b * 32 + i];
        }
        linv = 1.f / l;
    }
    __syncthreads();
    float s0 = 0.f, s1 = 0.f;
#pragma unroll
    for (int i = 0; i < 32; ++i) {
        const float wi = wgt[i];
        const float* cp = &ctx[(size_t)(b * 32 + i) * DD + tid * 2];
        s0 += wi * cp[0];
        s1 += wi * cp[1];
    }
    out[b * DD + tid * 2]     = s0 * linv;
    out[b * DD + tid * 2 + 1] = s1 * linv;
}

extern "C" void kernel_launch(void* const* d_in, const int* in_sizes, int n_in,
                              void* d_out, int out_size, void* d_ws, size_t ws_size,
                              hipStream_t stream) {
    const float* full = (const float*)d_in[0];
    const float* last = (const float*)d_in[1];
    const float* W1   = (const float*)d_in[2];
    const float* b1   = (const float*)d_in[3];
    const float* W2   = (const float*)d_in[4];
    const float* b2   = (const float*)d_in[5];
    const float* V    = (const float*)d_in[6];
    // d_in[7] = bV: softmax-invariant, unused.

    float* out   = (float*)d_out;
    float* h2    = (float*)d_ws;                    // 16384 floats
    float* m_arr = h2 + (size_t)BB * UU;            // 1024
    float* l_arr = m_arr + 1024;                    // 1024
    float* ctx   = l_arr + 1024;                    // 1024*512 = 524288
    short* W1T   = (short*)(ctx + (size_t)1024 * DD);     // U*D bf16

    prep_kernel<<<384, 256, 0, stream>>>(W1, W1T, last, W2, b1, b2, h2);
    score_kernel<<<BB * 32, 512, 0, stream>>>(full, W1T, h2, V, ctx, m_arr, l_arr);
    combine_kernel<<<BB, 256, 0, stream>>>(ctx, m_arr, l_arr, out);
}

// Round 6
// 260.760 us; speedup vs baseline: 1.3925x; 1.0840x over previous
//
#include <hip/hip_runtime.h>
#include <math.h>

// Attention pooling: context[b,d] = sum_t softmax_t( V . tanh(full[b,t,:]@W1 + last[b,:]@W2 + b1+b2) ) * full[b,t,d]
// B=32 T=2048 D=512 U=512, fp32 in/out. bV softmax-invariant -> dropped; b1+b2 folded into h2.
// R13: faithful m201-style phase-split port. Key diagnosis after R8..R12 all landed 95-112us:
//   every reg-destination global load in the K-loop lets the compiler insert its own conservative
//   s_waitcnt before the register use, silently defeating hand-counted vmcnt (the guide's
//   "HIP compiler defeats it" warning). Now the K-loop's ONLY vmcnt-counted ops are
//   global_load_lds DMAs (no dest regs) -> counted vmcnt(6) is real. A staged f32 via DMA,
//   converted to bf16 per-wave post-lgkm. 3 phases per K-tile (ds_read/DMA-issue of next work
//   overlaps MFMA of current via barrier-pair phases), setprio around MFMA clusters (T5 pays
//   only with phase-split: m218b). BM=128, BN=512(full U, needed for fused softmax), BK=32.
//   LDS 96KB: A dbuf f32 32K + B dbuf bf16 64K, epilogue scratch aliased into dead blds.
// ws (floats): h2 [B*U] @0, m_arr [512] @16384, l_arr [512] @16896, ctx [B*16*D] @17408,
//              W1T [U*D] bf16 @ float-offset 279552. Total ~1.64 MB.

#define BB 32
#define TT 2048
#define DD 512
#define UU 512
#define BKK 32
#define KSTEPS 16

typedef short bf16x8 __attribute__((ext_vector_type(8)));
typedef float f32x4  __attribute__((ext_vector_type(4)));

static __device__ __forceinline__ short f2bf(float f) {
    unsigned x = __float_as_uint(f);
    return (short)((x + 0x7fffu + ((x >> 16) & 1u)) >> 16);   // RNE
}

static __device__ __forceinline__ float fast_tanh(float x) {
    float e = __expf(2.f * x);
    return 1.f - 2.f * __builtin_amdgcn_rcpf(e + 1.f);
}

// ---------------- prep ----------------
// blocks [0,256): W1T[u][d] = bf16(W1[d][u]) tile-transposed
// blocks [256,384): h2 slice — block owns (b, 128-u-slice); threads d-split x2 + LDS combine
__global__ __launch_bounds__(256) void prep_kernel(const float* __restrict__ W1,
                                                   short* __restrict__ W1T,
                                                   const float* __restrict__ last,
                                                   const float* __restrict__ W2,
                                                   const float* __restrict__ b1,
                                                   const float* __restrict__ b2,
                                                   float* __restrict__ h2) {
    __shared__ float tile[32][33];
    __shared__ float ls[DD];
    __shared__ float part[256];
    const int bid = blockIdx.x;
    const int tid = threadIdx.x;
    if (bid < 256) {
        const int tr = (bid >> 4) << 5;   // d-block origin
        const int tc = (bid & 15) << 5;   // u-block origin
#pragma unroll
        for (int p = 0; p < 4; ++p) {
            const int r = p * 8 + (tid >> 5), c = tid & 31;
            tile[r][c] = W1[(size_t)(tr + r) * UU + tc + c];
        }
        __syncthreads();
#pragma unroll
        for (int p = 0; p < 4; ++p) {
            const int r = p * 8 + (tid >> 5), c = tid & 31;    // r=u-local, c=d-local
            W1T[(size_t)(tc + r) * DD + tr + c] = f2bf(tile[c][r]);
        }
    } else {
        const int b2i = bid - 256;
        const int b  = b2i >> 2;
        const int u0 = (b2i & 3) << 7;
        for (int i = tid; i < DD; i += 256) ls[i] = last[b * DD + i];
        __syncthreads();
        const int uu = tid & 127;
        const int dh = tid >> 7;
        float acc = 0.f;
#pragma unroll 8
        for (int d = dh * 256; d < dh * 256 + 256; ++d)
            acc += ls[d] * W2[d * UU + u0 + uu];
        part[tid] = acc;
        __syncthreads();
        if (tid < 128) {
            const int u = u0 + tid;
            h2[b * UU + u] = part[tid] + part[tid + 128] + b1[u] + b2[u];
        }
    }
}

// ---------------- score + partial context (flash-style, phase-split K-loop) ----------------
// 512 blocks: b = bid>>4, t0 = (bid&15)*128. 512 threads = 8 waves, 2(M) x 4(N);
// wave tile 64x128 (4 mt x 8 nt, acc[4][8]). K: 16 tiles of BK=32, A dbuf + B dbuf, per tile:
//   Ph0: ds_read A-frags f32 (8xb128) + bfrA[0..3] (4xb128); lgkm0+schedbar; cvt->af;
//        setprio1; 8 MFMA (nt=0,1); setprio0; s_barrier
//   Ph1: ds_read bfrB[0..3]; DMA A(ko+2)->a32[cur] (2x, A consumed in Ph0); lgkm0+schedbar;
//        setprio1; 8 MFMA (nt=2,3); setprio0; s_barrier
//   Ph2: DMA B(ko+2)->blds[cur] (4x, B consumed by Ph1 drain); setprio1; 16 MFMA (nt=4..7);
//        setprio0; vmcnt(6) [A(ko+1),B(ko+1) landed; (ko+2)'s 6 in flight]; s_barrier
// No register-destination global loads anywhere in the loop -> counted vmcnt is authoritative.
// LDS swizzles (both verified 2-way max = free): A slot(r,cc)=r*8+(cc^(r&7)) f32x4 chunks;
// B slot(u,kc)=u*4+(kc^((u>>1)&3)) bf16x8 chunks. Epilogue = R8's (proven).
__global__ __launch_bounds__(512) void score_kernel(const float* __restrict__ full,
                                                    const short* __restrict__ W1T,
                                                    const float* __restrict__ h2,
                                                    const float* __restrict__ V,
                                                    float* __restrict__ ctx,
                                                    float* __restrict__ m_arr,
                                                    float* __restrict__ l_arr) {
    __shared__ __align__(16) char smem[98304];
    float* a32  = (float*)smem;                      // [2][128*32] f32 (2 x 16 KB)
    short* blds = (short*)(smem + 32768);            // [2][512*32] bf16 (2 x 32 KB)
    // epilogue scratch aliased into blds (dead after K-loop final barrier):
    float (*red64)[64]    = (float(*)[64])(smem + 32768);            // 2048 B
    float* esc            = (float*)(smem + 32768 + 2048);           // 512 B
    float* sred           = (float*)(smem + 32768 + 2560);           // 32 B
    float (*red4)[128][4] = (float(*)[128][4])(smem + 32768 + 4096); // 8192 B

    const int bid  = blockIdx.x;
    const int b    = bid >> 4;
    const int t0   = (bid & 15) << 7;
    const int tid  = threadIdx.x;
    const int w    = tid >> 6;
    const int lane = tid & 63;
    const int quad = lane >> 4;
    const int col  = lane & 15;
    const int wm   = w >> 2;
    const int wn   = w & 3;

    const size_t fullbase = (size_t)(b * TT + t0) * DD;

    f32x4 acc[4][8];
#pragma unroll
    for (int i = 0; i < 4; ++i)
#pragma unroll
        for (int j = 0; j < 8; ++j) acc[i][j] = (f32x4){0.f, 0.f, 0.f, 0.f};

    // A DMA: 1024 f32x4 chunks/tile, 2 issues/thread. chunk s -> row r=s>>3, src chunk cc=(s&7)^(r&7).
#define STAGE_A(bufidx, koidx) do {                                                   \
        _Pragma("unroll")                                                             \
        for (int i = 0; i < 2; ++i) {                                                 \
            const int s  = i * 512 + w * 64 + lane;                                   \
            const int r  = s >> 3;                                                    \
            const int cc = (s & 7) ^ (r & 7);                                         \
            const float* g = &full[fullbase + (size_t)r * DD + (koidx) * BKK + cc * 4]; \
            __builtin_amdgcn_global_load_lds(                                         \
                (const __attribute__((address_space(1))) void*)g,                     \
                (__attribute__((address_space(3))) void*)&a32[(bufidx) * 4096 + s * 4], 16, 0, 0); \
        }                                                                             \
    } while (0)

    // B DMA: 2048 bf16x8 chunks/tile, 4 issues/thread. chunk s -> row u=s>>2, src chunk kc=(s&3)^((u>>1)&3).
#define STAGE_B(bufidx, koidx) do {                                                   \
        _Pragma("unroll")                                                             \
        for (int i = 0; i < 4; ++i) {                                                 \
            const int s  = i * 512 + w * 64 + lane;                                   \
            const int u  = s >> 2;                                                    \
            const int kc = (s & 3) ^ ((u >> 1) & 3);                                  \
            const short* g = &W1T[(size_t)u * DD + (koidx) * BKK + kc * 8];           \
            __builtin_amdgcn_global_load_lds(                                         \
                (const __attribute__((address_space(1))) void*)g,                     \
                (__attribute__((address_space(3))) void*)&blds[(bufidx) * 16384 + s * 8], 16, 0, 0); \
        }                                                                             \
    } while (0)

    // ---- prologue: A(0),A(1),B(0),B(1) all via DMA; drain through B(0); barrier ----
    STAGE_A(0, 0);
    STAGE_A(1, 1);
    STAGE_B(0, 0);
    STAGE_B(1, 1);
    asm volatile("s_waitcnt vmcnt(4)" ::: "memory");   // 12 out; leave B(1)x4 -> A0,A1,B0 landed
    __builtin_amdgcn_s_barrier();

    for (int ko = 0; ko < KSTEPS; ++ko) {
        const int cur = ko & 1;
        const int abase = cur * 4096;
        const int bbase = cur * 16384;

        // ================= Phase 0 =================
        f32x4 alo[4], ahi[4];
        bf16x8 bfrA[4];
#pragma unroll
        for (int mt = 0; mt < 4; ++mt) {
            const int r  = wm * 64 + mt * 16 + col;
            const int c0 = quad * 2;
            alo[mt] = *(const f32x4*)&a32[abase + (r * 8 + (c0 ^ (r & 7))) * 4];
            ahi[mt] = *(const f32x4*)&a32[abase + (r * 8 + ((c0 + 1) ^ (r & 7))) * 4];
        }
#pragma unroll
        for (int nt = 0; nt < 4; ++nt) {
            const int u = wn * 128 + nt * 16 + col;
            bfrA[nt] = *(const bf16x8*)&blds[bbase + (u * 4 + (quad ^ ((u >> 1) & 3))) * 8];
        }
        asm volatile("s_waitcnt lgkmcnt(0)" ::: "memory");
        __builtin_amdgcn_sched_barrier(0);             // rule 18: pin consumers below the wait
        bf16x8 af[4];
#pragma unroll
        for (int mt = 0; mt < 4; ++mt)
            af[mt] = (bf16x8){f2bf(alo[mt].x), f2bf(alo[mt].y), f2bf(alo[mt].z), f2bf(alo[mt].w),
                              f2bf(ahi[mt].x), f2bf(ahi[mt].y), f2bf(ahi[mt].z), f2bf(ahi[mt].w)};
        __builtin_amdgcn_s_setprio(1);
#pragma unroll
        for (int mt = 0; mt < 4; ++mt) {
            acc[mt][0] = __builtin_amdgcn_mfma_f32_16x16x32_bf16(af[mt], bfrA[0], acc[mt][0], 0, 0, 0);
            acc[mt][1] = __builtin_amdgcn_mfma_f32_16x16x32_bf16(af[mt], bfrA[1], acc[mt][1], 0, 0, 0);
        }
        __builtin_amdgcn_s_setprio(0);
        __builtin_amdgcn_s_barrier();                  // all waves done with A + bfrA reads

        // ================= Phase 1 =================
        bf16x8 bfrB[4];
#pragma unroll
        for (int nt = 0; nt < 4; ++nt) {
            const int u = wn * 128 + (nt + 4) * 16 + col;
            bfrB[nt] = *(const bf16x8*)&blds[bbase + (u * 4 + (quad ^ ((u >> 1) & 3))) * 8];
        }
        if (ko + 2 < KSTEPS) STAGE_A(cur, ko + 2);     // A[cur] consumed in Ph0 (barrier'd)
        asm volatile("s_waitcnt lgkmcnt(0)" ::: "memory");
        __builtin_amdgcn_sched_barrier(0);
        __builtin_amdgcn_s_setprio(1);
#pragma unroll
        for (int mt = 0; mt < 4; ++mt) {
            acc[mt][2] = __builtin_amdgcn_mfma_f32_16x16x32_bf16(af[mt], bfrA[2], acc[mt][2], 0, 0, 0);
            acc[mt][3] = __builtin_amdgcn_mfma_f32_16x16x32_bf16(af[mt], bfrA[3], acc[mt][3], 0, 0, 0);
        }
        __builtin_amdgcn_s_setprio(0);
        __builtin_amdgcn_s_barrier();                  // all waves done reading blds[cur]

        // ================= Phase 2 =================
        if (ko + 2 < KSTEPS) STAGE_B(cur, ko + 2);     // B[cur] consumed by Ph1 drain (barrier'd)
        __builtin_amdgcn_s_setprio(1);
#pragma unroll
        for (int mt = 0; mt < 4; ++mt) {
            acc[mt][4] = __builtin_amdgcn_mfma_f32_16x16x32_bf16(af[mt], bfrB[0], acc[mt][4], 0, 0, 0);
            acc[mt][5] = __builtin_amdgcn_mfma_f32_16x16x32_bf16(af[mt], bfrB[1], acc[mt][5], 0, 0, 0);
            acc[mt][6] = __builtin_amdgcn_mfma_f32_16x16x32_bf16(af[mt], bfrB[2], acc[mt][6], 0, 0, 0);
            acc[mt][7] = __builtin_amdgcn_mfma_f32_16x16x32_bf16(af[mt], bfrB[3], acc[mt][7], 0, 0, 0);
        }
        __builtin_amdgcn_s_setprio(0);
        // end-of-tile counted wait: require A(ko+1),B(ko+1) landed; (ko+2)'s 6 stay in flight
        if (ko <= KSTEPS - 3) {
            asm volatile("s_waitcnt vmcnt(6)" ::: "memory");
        } else if (ko == KSTEPS - 2) {
            asm volatile("s_waitcnt vmcnt(0)" ::: "memory");
        }
        __builtin_amdgcn_s_barrier();
    }
#undef STAGE_A
#undef STAGE_B

    // ---- raw scores: tanh + V-dot, reduce over this wave's 128 u, then over wn ----
    float srow[16];
#pragma unroll
    for (int i = 0; i < 16; ++i) srow[i] = 0.f;
#pragma unroll
    for (int nt = 0; nt < 8; ++nt) {
        const int u = wn * 128 + nt * 16 + col;
        const float hv = h2[b * UU + u];
        const float vv = V[u];
#pragma unroll
        for (int mt = 0; mt < 4; ++mt)
#pragma unroll
            for (int r = 0; r < 4; ++r)
                srow[mt * 4 + r] += fast_tanh(acc[mt][nt][r] + hv) * vv;
    }
#pragma unroll
    for (int off = 1; off < 16; off <<= 1) {
#pragma unroll
        for (int i = 0; i < 16; ++i) srow[i] += __shfl_xor(srow[i], off, 64);
    }
    // blds is dead (all reads drained before the K-loop's final barrier) -> scratch aliases safe
    if (col == 0) {
#pragma unroll
        for (int mt = 0; mt < 4; ++mt)
#pragma unroll
            for (int r = 0; r < 4; ++r)
                red64[w][mt * 16 + quad * 4 + r] = srow[mt * 4 + r];
    }
    __syncthreads();

    // ---- softmax stats over the 128 rows (threads 0..127 hold row tid) ----
    float sv = 0.f;
    if (tid < 128) {
        const int wmX = tid >> 6, rr = tid & 63;
        sv = red64[wmX * 4 + 0][rr] + red64[wmX * 4 + 1][rr] +
             red64[wmX * 4 + 2][rr] + red64[wmX * 4 + 3][rr];
        float mv = sv;
#pragma unroll
        for (int off = 1; off < 64; off <<= 1) mv = fmaxf(mv, __shfl_xor(mv, off, 64));
        if (lane == 0) sred[w] = mv;
    }
    __syncthreads();
    const float M = fmaxf(sred[0], sred[1]);
    if (tid < 128) {
        float e = __expf(sv - M);
        esc[tid] = e;
#pragma unroll
        for (int off = 1; off < 64; off <<= 1) e += __shfl_xor(e, off, 64);
        if (lane == 0) sred[4 + w] = e;
    }
    __syncthreads();
    if (tid == 0) { m_arr[bid] = M; l_arr[bid] = sred[4] + sred[5]; }

    // ---- partial context from the (L2-hot) tile: ctx[d] = sum_t esc[t] * full[t,d] ----
    const int c  = tid & 127;             // float4 column, d = c*4
    const int tp = tid >> 7;              // t residue mod 4
    float ax = 0.f, ay = 0.f, az = 0.f, aw = 0.f;
#pragma unroll 4
    for (int i = 0; i < 32; ++i) {
        const int t = i * 4 + tp;
        const float4 v = *(const float4*)&full[fullbase + (size_t)t * DD + c * 4];
        const float e = esc[t];
        ax += e * v.x; ay += e * v.y; az += e * v.z; aw += e * v.w;
    }
    *(float4*)&red4[tp][c][0] = make_float4(ax, ay, az, aw);
    __syncthreads();
    if (tp == 0) {
        const float4 p0 = *(const float4*)&red4[0][c][0];
        const float4 p1 = *(const float4*)&red4[1][c][0];
        const float4 p2 = *(const float4*)&red4[2][c][0];
        const float4 p3 = *(const float4*)&red4[3][c][0];
        float4 s = make_float4(p0.x + p1.x + p2.x + p3.x,
                               p0.y + p1.y + p2.y + p3.y,
                               p0.z + p1.z + p2.z + p3.z,
                               p0.w + p1.w + p2.w + p3.w);
        *(float4*)&ctx[(size_t)bid * DD + c * 4] = s;
    }
}

// ---------------- combine: out[b,d] = sum_i w_i*ctx[b,i,d] / sum_i w_i*l_i, w_i = e^{m_i - M} ----------------
__global__ __launch_bounds__(256) void combine_kernel(const float* __restrict__ ctx,
                                                      const float* __restrict__ m_arr,
                                                      const float* __restrict__ l_arr,
                                                      float* __restrict__ out) {
    const int b = blockIdx.x;
    const int tid = threadIdx.x;
    __shared__ float wgt[16];
    __shared__ float linv;
    if (tid == 0) {
        float M = -1e30f;
#pragma unroll
        for (int i = 0; i < 16; ++i) M = fmaxf(M, m_arr[b * 16 + i]);
        float l = 0.f;
#pragma unroll
        for (int i = 0; i < 16; ++i) {
            wgt[i] = __expf(m_arr[b * 16 + i] - M);
            l += wgt[i] * l_arr[b * 16 + i];
        }
        linv = 1.f / l;
    }
    __syncthreads();
    float s0 = 0.f, s1 = 0.f;
#pragma unroll
    for (int i = 0; i < 16; ++i) {
        const float wi = wgt[i];
        const float* cp = &ctx[(size_t)(b * 16 + i) * DD + tid * 2];
        s0 += wi * cp[0];
        s1 += wi * cp[1];
    }
    out[b * DD + tid * 2]     = s0 * linv;
    out[b * DD + tid * 2 + 1] = s1 * linv;
}

extern "C" void kernel_launch(void* const* d_in, const int* in_sizes, int n_in,
                              void* d_out, int out_size, void* d_ws, size_t ws_size,
                              hipStream_t stream) {
    const float* full = (const float*)d_in[0];
    const float* last = (const float*)d_in[1];
    const float* W1   = (const float*)d_in[2];
    const float* b1   = (const float*)d_in[3];
    const float* W2   = (const float*)d_in[4];
    const float* b2   = (const float*)d_in[5];
    const float* V    = (const float*)d_in[6];
    // d_in[7] = bV: softmax-invariant, unused.

    float* out   = (float*)d_out;
    float* h2    = (float*)d_ws;                    // 16384 floats
    float* m_arr = h2 + (size_t)BB * UU;            // 512
    float* l_arr = m_arr + 512;                     // 512
    float* ctx   = l_arr + 512;                     // 32*16*512 = 262144
    short* W1T   = (short*)(ctx + (size_t)BB * 16 * DD);  // U*D bf16

    prep_kernel<<<384, 256, 0, stream>>>(W1, W1T, last, W2, b1, b2, h2);
    score_kernel<<<BB * 16, 512, 0, stream>>>(full, W1T, h2, V, ctx, m_arr, l_arr);
    combine_kernel<<<BB, 256, 0, stream>>>(ctx, m_arr, l_arr, out);
}